// Round 9
// baseline (400.699 us; speedup 1.0000x reference)
//
#include <hip/hip_runtime.h>
#include <math.h>

#define DD 128
#define HH 16
#define EPSV 1e-5f

static __device__ __forceinline__ ushort f2bf(float f) {
  uint u = __float_as_uint(f);
  u += 0x7FFFu + ((u >> 16) & 1u);
  return (ushort)(u >> 16);
}
static __device__ __forceinline__ float bflo(uint u) { return __uint_as_float(u << 16); }
static __device__ __forceinline__ float bfhi(uint u) { return __uint_as_float(u & 0xFFFF0000u); }

// ---------------- CSR build ----------------

__global__ void k_hist(const int* __restrict__ dst, int* __restrict__ deg, int ecnt) {
  int e = blockIdx.x * blockDim.x + threadIdx.x;
  if (e < ecnt) atomicAdd(&deg[dst[e]], 1);
}

__global__ void k_dinv(const int* __restrict__ deg, float* __restrict__ dinv, int n) {
  int i = blockIdx.x * blockDim.x + threadIdx.x;
  if (i < n) dinv[i] = rsqrtf((float)deg[i] + 2.0f);
}

#define SCAN_T 1024
#define SCAN_I 4

__global__ void k_scan1(const int* __restrict__ deg, int* __restrict__ bsum, int n) {
  __shared__ int sh[SCAN_T];
  int tid = threadIdx.x;
  int base = blockIdx.x * SCAN_T * SCAN_I + tid * SCAN_I;
  int s = 0;
#pragma unroll
  for (int j = 0; j < SCAN_I; ++j) { int i = base + j; if (i < n) s += deg[i]; }
  sh[tid] = s;
  __syncthreads();
  for (int off = SCAN_T / 2; off > 0; off >>= 1) {
    if (tid < off) sh[tid] += sh[tid + off];
    __syncthreads();
  }
  if (tid == 0) bsum[blockIdx.x] = sh[0];
}

__global__ void k_scan2(const int* __restrict__ deg, const int* __restrict__ bsum,
                        int* __restrict__ rowoff, int n) {
  __shared__ int sh[SCAN_T];
  __shared__ int sbase;
  int tid = threadIdx.x;
  int b = blockIdx.x;
  if (tid == 0) { int s = 0; for (int j = 0; j < b; ++j) s += bsum[j]; sbase = s; }
  int base = b * SCAN_T * SCAN_I + tid * SCAN_I;
  int d[SCAN_I]; int ts = 0;
#pragma unroll
  for (int j = 0; j < SCAN_I; ++j) { int i = base + j; d[j] = (i < n) ? deg[i] : 0; ts += d[j]; }
  sh[tid] = ts;
  __syncthreads();
  for (int off = 1; off < SCAN_T; off <<= 1) {
    int v = (tid >= off) ? sh[tid - off] : 0;
    __syncthreads();
    sh[tid] += v;
    __syncthreads();
  }
  int ex = sbase + sh[tid] - ts;
#pragma unroll
  for (int j = 0; j < SCAN_I; ++j) {
    int i = base + j;
    if (i < n) rowoff[i] = ex;
    ex += d[j];
  }
}

__global__ void k_fill(const int* __restrict__ src, const int* __restrict__ dst,
                       const float* __restrict__ dinv, const int* __restrict__ rowoff,
                       int* __restrict__ cursor, int2* __restrict__ csr, int ecnt) {
  int e = blockIdx.x * blockDim.x + threadIdx.x;
  if (e >= ecnt) return;
  int s = src[e], d = dst[e];
  int p = atomicAdd(&cursor[d], 1);
  float nw = dinv[s] * dinv[d];
  csr[rowoff[d] + p] = make_int2(s, __float_as_int(nw));
}

// ---------------- GEMM: C_bf16[nrows,128] = A_f32[nrows,128] @ B[128,128] ----------------

__global__ __launch_bounds__(256) void k_gemm(const float* __restrict__ A,
                                              const float* __restrict__ B,
                                              ushort* __restrict__ C, int nrows) {
  __shared__ float Bs[DD * 64];
  int tid = threadIdx.x;
  int tx = tid & 15, ty = tid >> 4;
  int rowbase = blockIdx.x * 128;
  int c0 = blockIdx.y * 64;
  {
    int kk = tid >> 4;
    int cc = (tid & 15) * 4;
#pragma unroll
    for (int p = 0; p < 8; ++p) {
      int k = p * 16 + kk;
      float4 bv = *reinterpret_cast<const float4*>(&B[k * DD + c0 + cc]);
      *reinterpret_cast<float4*>(&Bs[k * 64 + cc]) = bv;
    }
  }
  __syncthreads();
  float acc[8][4];
#pragma unroll
  for (int i = 0; i < 8; ++i)
#pragma unroll
    for (int j = 0; j < 4; ++j) acc[i][j] = 0.f;
  int rl[8];
#pragma unroll
  for (int i = 0; i < 8; ++i) {
    int r = rowbase + ty * 8 + i;
    rl[i] = (r < nrows) ? r : (nrows - 1);
  }
  const float4* A4 = reinterpret_cast<const float4*>(A);
  for (int kq = 0; kq < 32; ++kq) {
    float4 av[8];
#pragma unroll
    for (int i = 0; i < 8; ++i) av[i] = A4[(size_t)rl[i] * 32 + kq];
#pragma unroll
    for (int j = 0; j < 4; ++j) {
      float4 bv = *reinterpret_cast<const float4*>(&Bs[(kq * 4 + j) * 64 + tx * 4]);
#pragma unroll
      for (int i = 0; i < 8; ++i) {
        float a = (j == 0) ? av[i].x : (j == 1) ? av[i].y : (j == 2) ? av[i].z : av[i].w;
        acc[i][0] = fmaf(a, bv.x, acc[i][0]);
        acc[i][1] = fmaf(a, bv.y, acc[i][1]);
        acc[i][2] = fmaf(a, bv.z, acc[i][2]);
        acc[i][3] = fmaf(a, bv.w, acc[i][3]);
      }
    }
  }
  int cbase = c0 + tx * 4;
#pragma unroll
  for (int i = 0; i < 8; ++i) {
    int r = rowbase + ty * 8 + i;
    if (r < nrows) {
      ushort4 o;
      o.x = f2bf(acc[i][0]); o.y = f2bf(acc[i][1]);
      o.z = f2bf(acc[i][2]); o.w = f2bf(acc[i][3]);
      *reinterpret_cast<ushort4*>(&C[(size_t)r * DD + cbase]) = o;
    }
  }
}

// ---------------- edge accumulate: dwordx4 gathers, 4 edges per instruction --------------
// Wave = node i; 4 groups x 16 lanes. Group g handles edge slot base+g; lane l of a
// group owns dims 8l..8l+7 (one uint4 = 16B of the 256B row). One gather instruction
// moves 1KB = 4 full edge rows. a[8] accumulates per-lane; caller reduces over groups.

#define FMA8(vv, nw)                          \
  a[0] = fmaf(bflo((vv).x), (nw), a[0]);      \
  a[1] = fmaf(bfhi((vv).x), (nw), a[1]);      \
  a[2] = fmaf(bflo((vv).y), (nw), a[2]);      \
  a[3] = fmaf(bfhi((vv).y), (nw), a[3]);      \
  a[4] = fmaf(bflo((vv).z), (nw), a[4]);      \
  a[5] = fmaf(bfhi((vv).z), (nw), a[5]);      \
  a[6] = fmaf(bflo((vv).w), (nw), a[6]);      \
  a[7] = fmaf(bfhi((vv).w), (nw), a[7]);

static __device__ __forceinline__ void edge_accum16(
    const uint4* __restrict__ xw16, const int2* __restrict__ cs,
    int cnt, int g, int l, float* a) {
  int e = 0;
  int2 ce[4];
  if (cnt >= 16) {
#pragma unroll
    for (int jj = 0; jj < 4; ++jj) ce[jj] = cs[4 * jj + g];
  }
  while (e + 32 <= cnt) {
    uint4 v[4];
#pragma unroll
    for (int jj = 0; jj < 4; ++jj) v[jj] = xw16[((uint)ce[jj].x << 4) + l];
    int2 cn[4];
#pragma unroll
    for (int jj = 0; jj < 4; ++jj) cn[jj] = cs[e + 16 + 4 * jj + g];
#pragma unroll
    for (int jj = 0; jj < 4; ++jj) {
      float nw = __int_as_float(ce[jj].y);
      FMA8(v[jj], nw);
    }
#pragma unroll
    for (int jj = 0; jj < 4; ++jj) ce[jj] = cn[jj];
    e += 16;
  }
  if (e + 16 <= cnt) {
    uint4 v[4];
#pragma unroll
    for (int jj = 0; jj < 4; ++jj) v[jj] = xw16[((uint)ce[jj].x << 4) + l];
#pragma unroll
    for (int jj = 0; jj < 4; ++jj) {
      float nw = __int_as_float(ce[jj].y);
      FMA8(v[jj], nw);
    }
    e += 16;
  }
  while (e + 4 <= cnt) {
    int2 c = cs[e + g];
    uint4 v = xw16[((uint)c.x << 4) + l];
    float nw = __int_as_float(c.y);
    FMA8(v, nw);
    e += 4;
  }
  if (e < cnt) {
    int k = e + g;
    bool act = k < cnt;
    int2 c = cs[act ? k : e];
    float nw = act ? __int_as_float(c.y) : 0.f;
    uint4 v = xw16[((uint)c.x << 4) + l];
    FMA8(v, nw);
  }
}

// ---------------- agg1: gather + self + bias + LN + ReLU -> fp32 h1 ----------------

__global__ __launch_bounds__(256) void k_agg1(
    const ushort* __restrict__ xw, const int2* __restrict__ csr,
    const int* __restrict__ rowoff, const int* __restrict__ deg,
    const float* __restrict__ dinv, const float* __restrict__ bias,
    const float* __restrict__ gam, const float* __restrict__ bet,
    float* __restrict__ outp, int n) {
  int wv = threadIdx.x >> 6, lane = threadIdx.x & 63;
  int i = blockIdx.x * 4 + wv;
  if (i >= n) return;
  int g = lane >> 4, l = lane & 15;
  int start = rowoff[i], cnt = deg[i];
  float di = dinv[i];
  const uint4* xw16 = (const uint4*)xw;
  float a[8] = {0.f, 0.f, 0.f, 0.f, 0.f, 0.f, 0.f, 0.f};
  edge_accum16(xw16, csr + start, cnt, g, l, a);
#pragma unroll
  for (int k = 0; k < 8; ++k) {
    a[k] += __shfl_xor(a[k], 16);
    a[k] += __shfl_xor(a[k], 32);
  }
  // self-loop + bias after the cross-group combine
  uint4 su = xw16[((uint)i << 4) + l];
  float sw = 2.f * di * di;
  float4 b0 = ((const float4*)bias)[2 * l];
  float4 b1 = ((const float4*)bias)[2 * l + 1];
  a[0] = fmaf(bflo(su.x), sw, a[0]) + b0.x;
  a[1] = fmaf(bfhi(su.x), sw, a[1]) + b0.y;
  a[2] = fmaf(bflo(su.y), sw, a[2]) + b0.z;
  a[3] = fmaf(bfhi(su.y), sw, a[3]) + b0.w;
  a[4] = fmaf(bflo(su.z), sw, a[4]) + b1.x;
  a[5] = fmaf(bfhi(su.z), sw, a[5]) + b1.y;
  a[6] = fmaf(bflo(su.w), sw, a[6]) + b1.z;
  a[7] = fmaf(bfhi(su.w), sw, a[7]) + b1.w;
  // LayerNorm over 128 dims: 8 local + 16-lane shuffle reduce
  float s = ((a[0] + a[1]) + (a[2] + a[3])) + ((a[4] + a[5]) + (a[6] + a[7]));
#pragma unroll
  for (int off = 8; off > 0; off >>= 1) s += __shfl_xor(s, off);
  float mu = s * (1.f / DD);
  float c[8];
  float q = 0.f;
#pragma unroll
  for (int k = 0; k < 8; ++k) { c[k] = a[k] - mu; q = fmaf(c[k], c[k], q); }
#pragma unroll
  for (int off = 8; off > 0; off >>= 1) q += __shfl_xor(q, off);
  float rstd = rsqrtf(q * (1.f / DD) + EPSV);
  float4 g0 = ((const float4*)gam)[2 * l], g1 = ((const float4*)gam)[2 * l + 1];
  float4 t0 = ((const float4*)bet)[2 * l], t1 = ((const float4*)bet)[2 * l + 1];
  if (g == 0) {
    float4 o0, o1;
    o0.x = fmaxf(fmaf(c[0] * rstd, g0.x, t0.x), 0.f);
    o0.y = fmaxf(fmaf(c[1] * rstd, g0.y, t0.y), 0.f);
    o0.z = fmaxf(fmaf(c[2] * rstd, g0.z, t0.z), 0.f);
    o0.w = fmaxf(fmaf(c[3] * rstd, g0.w, t0.w), 0.f);
    o1.x = fmaxf(fmaf(c[4] * rstd, g1.x, t1.x), 0.f);
    o1.y = fmaxf(fmaf(c[5] * rstd, g1.y, t1.y), 0.f);
    o1.z = fmaxf(fmaf(c[6] * rstd, g1.z, t1.z), 0.f);
    o1.w = fmaxf(fmaf(c[7] * rstd, g1.w, t1.w), 0.f);
    ((float4*)(outp + (size_t)i * DD))[2 * l] = o0;
    ((float4*)(outp + (size_t)i * DD))[2 * l + 1] = o1;
  }
}

// ---------------- agg2: gather + LN + SE + residual + ReLU -> fp32 out ----------------
// SE hidden dim (16) partitioned across the 4 groups (group g owns j=4g..4g+3).

__global__ __launch_bounds__(256) void k_agg2(
    const ushort* __restrict__ xw, const int2* __restrict__ csr,
    const int* __restrict__ rowoff, const int* __restrict__ deg,
    const float* __restrict__ dinv, const float* __restrict__ bias,
    const float* __restrict__ gam, const float* __restrict__ bet,
    const float* __restrict__ Ws, const float* __restrict__ bs,
    const float* __restrict__ We, const float* __restrict__ be,
    const float* __restrict__ xin, float* __restrict__ outp, int n) {
  int wv = threadIdx.x >> 6, lane = threadIdx.x & 63;
  int i = blockIdx.x * 4 + wv;
  if (i >= n) return;
  int g = lane >> 4, l = lane & 15;
  int start = rowoff[i], cnt = deg[i];
  float di = dinv[i];
  const uint4* xw16 = (const uint4*)xw;
  float a[8] = {0.f, 0.f, 0.f, 0.f, 0.f, 0.f, 0.f, 0.f};
  edge_accum16(xw16, csr + start, cnt, g, l, a);
#pragma unroll
  for (int k = 0; k < 8; ++k) {
    a[k] += __shfl_xor(a[k], 16);
    a[k] += __shfl_xor(a[k], 32);
  }
  uint4 su = xw16[((uint)i << 4) + l];
  float sw = 2.f * di * di;
  float4 b0 = ((const float4*)bias)[2 * l];
  float4 b1 = ((const float4*)bias)[2 * l + 1];
  a[0] = fmaf(bflo(su.x), sw, a[0]) + b0.x;
  a[1] = fmaf(bfhi(su.x), sw, a[1]) + b0.y;
  a[2] = fmaf(bflo(su.y), sw, a[2]) + b0.z;
  a[3] = fmaf(bfhi(su.y), sw, a[3]) + b0.w;
  a[4] = fmaf(bflo(su.z), sw, a[4]) + b1.x;
  a[5] = fmaf(bfhi(su.z), sw, a[5]) + b1.y;
  a[6] = fmaf(bflo(su.w), sw, a[6]) + b1.z;
  a[7] = fmaf(bfhi(su.w), sw, a[7]) + b1.w;
  // LayerNorm
  float s = ((a[0] + a[1]) + (a[2] + a[3])) + ((a[4] + a[5]) + (a[6] + a[7]));
#pragma unroll
  for (int off = 8; off > 0; off >>= 1) s += __shfl_xor(s, off);
  float mu = s * (1.f / DD);
  float c[8];
  float q = 0.f;
#pragma unroll
  for (int k = 0; k < 8; ++k) { c[k] = a[k] - mu; q = fmaf(c[k], c[k], q); }
#pragma unroll
  for (int off = 8; off > 0; off >>= 1) q += __shfl_xor(q, off);
  float rstd = rsqrtf(q * (1.f / DD) + EPSV);
  float4 g0 = ((const float4*)gam)[2 * l], g1 = ((const float4*)gam)[2 * l + 1];
  float4 t0 = ((const float4*)bet)[2 * l], t1 = ((const float4*)bet)[2 * l + 1];
  float h[8];
  h[0] = fmaf(c[0] * rstd, g0.x, t0.x);
  h[1] = fmaf(c[1] * rstd, g0.y, t0.y);
  h[2] = fmaf(c[2] * rstd, g0.z, t0.z);
  h[3] = fmaf(c[3] * rstd, g0.w, t0.w);
  h[4] = fmaf(c[4] * rstd, g1.x, t1.x);
  h[5] = fmaf(c[5] * rstd, g1.y, t1.y);
  h[6] = fmaf(c[6] * rstd, g1.z, t1.z);
  h[7] = fmaf(c[7] * rstd, g1.w, t1.w);
  // SE stage 1: group g computes pj for j = 4g..4g+3
  float pj0 = 0.f, pj1 = 0.f, pj2 = 0.f, pj3 = 0.f;
#pragma unroll
  for (int k = 0; k < 8; ++k) {
    float4 wsv = *(const float4*)&Ws[(8 * l + k) * HH + 4 * g];
    pj0 = fmaf(h[k], wsv.x, pj0);
    pj1 = fmaf(h[k], wsv.y, pj1);
    pj2 = fmaf(h[k], wsv.z, pj2);
    pj3 = fmaf(h[k], wsv.w, pj3);
  }
#pragma unroll
  for (int off = 8; off > 0; off >>= 1) {
    pj0 += __shfl_xor(pj0, off);
    pj1 += __shfl_xor(pj1, off);
    pj2 += __shfl_xor(pj2, off);
    pj3 += __shfl_xor(pj3, off);
  }
  float4 bsv = ((const float4*)bs)[g];
  float s0 = fmaxf(pj0 + bsv.x, 0.f);
  float s1 = fmaxf(pj1 + bsv.y, 0.f);
  float s2 = fmaxf(pj2 + bsv.z, 0.f);
  float s3 = fmaxf(pj3 + bsv.w, 0.f);
  // SE stage 2: group g accumulates its 4 j-rows of We into w[8]
  float w[8] = {0.f, 0.f, 0.f, 0.f, 0.f, 0.f, 0.f, 0.f};
#pragma unroll
  for (int jj = 0; jj < 4; ++jj) {
    float sj = (jj == 0) ? s0 : (jj == 1) ? s1 : (jj == 2) ? s2 : s3;
    const float4* wer = (const float4*)&We[(4 * g + jj) * DD + 8 * l];
    float4 w0v = wer[0], w1v = wer[1];
    w[0] = fmaf(sj, w0v.x, w[0]);
    w[1] = fmaf(sj, w0v.y, w[1]);
    w[2] = fmaf(sj, w0v.z, w[2]);
    w[3] = fmaf(sj, w0v.w, w[3]);
    w[4] = fmaf(sj, w1v.x, w[4]);
    w[5] = fmaf(sj, w1v.y, w[5]);
    w[6] = fmaf(sj, w1v.z, w[6]);
    w[7] = fmaf(sj, w1v.w, w[7]);
  }
#pragma unroll
  for (int k = 0; k < 8; ++k) {
    w[k] += __shfl_xor(w[k], 16);
    w[k] += __shfl_xor(w[k], 32);
  }
  if (g == 0) {
    float4 e0 = ((const float4*)be)[2 * l], e1 = ((const float4*)be)[2 * l + 1];
    float4 xr0 = ((const float4*)(xin + (size_t)i * DD))[2 * l];
    float4 xr1 = ((const float4*)(xin + (size_t)i * DD))[2 * l + 1];
    float gt[8];
    gt[0] = 1.f / (1.f + __expf(-(w[0] + e0.x)));
    gt[1] = 1.f / (1.f + __expf(-(w[1] + e0.y)));
    gt[2] = 1.f / (1.f + __expf(-(w[2] + e0.z)));
    gt[3] = 1.f / (1.f + __expf(-(w[3] + e0.w)));
    gt[4] = 1.f / (1.f + __expf(-(w[4] + e1.x)));
    gt[5] = 1.f / (1.f + __expf(-(w[5] + e1.y)));
    gt[6] = 1.f / (1.f + __expf(-(w[6] + e1.z)));
    gt[7] = 1.f / (1.f + __expf(-(w[7] + e1.w)));
    float4 o0, o1;
    o0.x = fmaxf(fmaf(h[0], gt[0], xr0.x), 0.f);
    o0.y = fmaxf(fmaf(h[1], gt[1], xr0.y), 0.f);
    o0.z = fmaxf(fmaf(h[2], gt[2], xr0.z), 0.f);
    o0.w = fmaxf(fmaf(h[3], gt[3], xr0.w), 0.f);
    o1.x = fmaxf(fmaf(h[4], gt[4], xr1.x), 0.f);
    o1.y = fmaxf(fmaf(h[5], gt[5], xr1.y), 0.f);
    o1.z = fmaxf(fmaf(h[6], gt[6], xr1.z), 0.f);
    o1.w = fmaxf(fmaf(h[7], gt[7], xr1.w), 0.f);
    ((float4*)(outp + (size_t)i * DD))[2 * l] = o0;
    ((float4*)(outp + (size_t)i * DD))[2 * l + 1] = o1;
  }
}

// ---------------- launcher ----------------

extern "C" void kernel_launch(void* const* d_in, const int* in_sizes, int n_in,
                              void* d_out, int out_size, void* d_ws, size_t ws_size,
                              hipStream_t stream) {
  const float* x   = (const float*)d_in[0];
  const int*   ei  = (const int*)d_in[1];
  const float* W1  = (const float*)d_in[2];
  const float* b1  = (const float*)d_in[3];
  const float* g1  = (const float*)d_in[4];
  const float* be1 = (const float*)d_in[5];
  const float* W2  = (const float*)d_in[6];
  const float* b2  = (const float*)d_in[7];
  const float* g2  = (const float*)d_in[8];
  const float* be2 = (const float*)d_in[9];
  const float* Ws  = (const float*)d_in[10];
  const float* bs  = (const float*)d_in[11];
  const float* We  = (const float*)d_in[12];
  const float* bee = (const float*)d_in[13];
  float* outp = (float*)d_out;

  int n    = in_sizes[0] / DD;
  int ecnt = in_sizes[1] / 2;
  const int* src = ei;
  const int* dst = ei + ecnt;

  char* w = (char*)d_ws;
  ushort* xw    = (ushort*)w; w += (size_t)n * DD * 2;
  float*  h1    = (float*)w;  w += (size_t)n * DD * 4;
  int*    deg   = (int*)w;    w += (size_t)n * 4;
  int*    cursor= (int*)w;    w += (size_t)n * 4;  // adjacent to deg (one memset)
  int*    rowoff= (int*)w;    w += (size_t)n * 4;
  float*  dinv  = (float*)w;  w += (size_t)n * 4;
  int*    bsum  = (int*)w;    w += 64 * 4;
  int2*   csr   = (int2*)w;   w += ((size_t)ecnt + 32) * 8;  // +32: tail batch overread pad

  hipMemsetAsync(deg, 0, (size_t)n * 8, stream);  // deg + cursor

  const int TB = 256;
  int eb = (ecnt + TB - 1) / TB;
  int nbk = (n + TB - 1) / TB;
  k_hist<<<eb, TB, 0, stream>>>(dst, deg, ecnt);
  k_dinv<<<nbk, TB, 0, stream>>>(deg, dinv, n);
  int nb = (n + SCAN_T * SCAN_I - 1) / (SCAN_T * SCAN_I);
  k_scan1<<<nb, SCAN_T, 0, stream>>>(deg, bsum, n);
  k_scan2<<<nb, SCAN_T, 0, stream>>>(deg, bsum, rowoff, n);
  k_fill<<<eb, TB, 0, stream>>>(src, dst, dinv, rowoff, cursor, csr, ecnt);

  dim3 gg((n + 127) / 128, 2);
  int nb4 = (n + 3) / 4;
  k_gemm<<<gg, 256, 0, stream>>>(x, W1, xw, n);
  k_agg1<<<nb4, 256, 0, stream>>>(xw, csr, rowoff, deg, dinv, b1, g1, be1, h1, n);
  k_gemm<<<gg, 256, 0, stream>>>(h1, W2, xw, n);
  k_agg2<<<nb4, 256, 0, stream>>>(xw, csr, rowoff, deg, dinv, b2, g2, be2,
                                  Ws, bs, We, bee, x, outp, n);
}

// Round 10
// 371.952 us; speedup vs baseline: 1.0773x; 1.0773x over previous
//
#include <hip/hip_runtime.h>
#include <hip/hip_fp16.h>
#include <math.h>

#define DD 128
#define HH 16
#define EPSV 1e-5f

static __device__ __forceinline__ ushort f2bf(float f) {
  uint u = __float_as_uint(f);
  u += 0x7FFFu + ((u >> 16) & 1u);
  return (ushort)(u >> 16);
}
static __device__ __forceinline__ float bflo(uint u) { return __uint_as_float(u << 16); }
static __device__ __forceinline__ float bfhi(uint u) { return __uint_as_float(u & 0xFFFF0000u); }

// ---------------- scans ----------------

#define SCAN_T 1024
#define SCAN_I 4

__global__ void k_scan1(const int* __restrict__ deg, int* __restrict__ bsum, int n) {
  __shared__ int sh[SCAN_T];
  int tid = threadIdx.x;
  int base = blockIdx.x * SCAN_T * SCAN_I + tid * SCAN_I;
  int s = 0;
#pragma unroll
  for (int j = 0; j < SCAN_I; ++j) { int i = base + j; if (i < n) s += deg[i]; }
  sh[tid] = s;
  __syncthreads();
  for (int off = SCAN_T / 2; off > 0; off >>= 1) {
    if (tid < off) sh[tid] += sh[tid + off];
    __syncthreads();
  }
  if (tid == 0) bsum[blockIdx.x] = sh[0];
}

// scan2 also emits dinv[] and pre-fills cursor[] = rowoff[]
__global__ void k_scan2(const int* __restrict__ deg, const int* __restrict__ bsum,
                        int* __restrict__ rowoff, int* __restrict__ cursor,
                        float* __restrict__ dinv, int n) {
  __shared__ int sh[SCAN_T];
  __shared__ int sbase;
  int tid = threadIdx.x;
  int b = blockIdx.x;
  if (tid == 0) { int s = 0; for (int j = 0; j < b; ++j) s += bsum[j]; sbase = s; }
  int base = b * SCAN_T * SCAN_I + tid * SCAN_I;
  int d[SCAN_I]; int ts = 0;
#pragma unroll
  for (int j = 0; j < SCAN_I; ++j) { int i = base + j; d[j] = (i < n) ? deg[i] : 0; ts += d[j]; }
  sh[tid] = ts;
  __syncthreads();
  for (int off = 1; off < SCAN_T; off <<= 1) {
    int v = (tid >= off) ? sh[tid - off] : 0;
    __syncthreads();
    sh[tid] += v;
    __syncthreads();
  }
  int ex = sbase + sh[tid] - ts;
#pragma unroll
  for (int j = 0; j < SCAN_I; ++j) {
    int i = base + j;
    if (i < n) {
      rowoff[i] = ex;
      cursor[i] = ex;
      dinv[i] = rsqrtf((float)d[j] + 2.0f);
    }
    ex += d[j];
  }
}

// fill: 4B packed CSR entry = (fp16(nw) << 16) | u16(src); cursor pre-filled = rowoff
__global__ void k_fill(const int* __restrict__ src, const int* __restrict__ dst,
                       const float* __restrict__ dinv, int* __restrict__ cursor,
                       uint* __restrict__ csr, int ecnt) {
  int e = blockIdx.x * blockDim.x + threadIdx.x;
  if (e >= ecnt) return;
  int s = src[e], d = dst[e];
  int idx = atomicAdd(&cursor[d], 1);
  float nw = dinv[s] * dinv[d];
  uint hb = (uint)__half_as_ushort(__float2half_rn(nw));
  __builtin_nontemporal_store((hb << 16) | (uint)s, &csr[idx]);
}

// ---------------- GEMM1 (fp32 A) fused with degree histogram ----------------
// blocks [0, gblocks): GEMM tiles (bx>>1 = row tile, bx&1 = col half)
// blocks [gblocks, gblocks+hblocks): grid-stride histogram over edges

static __device__ __forceinline__ void gemm_f32_body(
    const float* __restrict__ A, const float* __restrict__ B,
    ushort* __restrict__ C, int nrows, int bx, float* Bs) {
  int tid = threadIdx.x;
  int tx = tid & 15, ty = tid >> 4;
  int rowbase = (bx >> 1) * 128;
  int c0 = (bx & 1) * 64;
  {
    int kk = tid >> 4;
    int cc = (tid & 15) * 4;
#pragma unroll
    for (int p = 0; p < 8; ++p) {
      int k = p * 16 + kk;
      float4 bv = *reinterpret_cast<const float4*>(&B[k * DD + c0 + cc]);
      *reinterpret_cast<float4*>(&Bs[k * 64 + cc]) = bv;
    }
  }
  __syncthreads();
  float acc[8][4];
#pragma unroll
  for (int i = 0; i < 8; ++i)
#pragma unroll
    for (int j = 0; j < 4; ++j) acc[i][j] = 0.f;
  int rl[8];
#pragma unroll
  for (int i = 0; i < 8; ++i) {
    int r = rowbase + ty * 8 + i;
    rl[i] = (r < nrows) ? r : (nrows - 1);
  }
  const float4* A4 = reinterpret_cast<const float4*>(A);
  for (int kq = 0; kq < 32; ++kq) {
    float4 av[8];
#pragma unroll
    for (int i = 0; i < 8; ++i) av[i] = A4[(size_t)rl[i] * 32 + kq];
#pragma unroll
    for (int j = 0; j < 4; ++j) {
      float4 bv = *reinterpret_cast<const float4*>(&Bs[(kq * 4 + j) * 64 + tx * 4]);
#pragma unroll
      for (int i = 0; i < 8; ++i) {
        float a = (j == 0) ? av[i].x : (j == 1) ? av[i].y : (j == 2) ? av[i].z : av[i].w;
        acc[i][0] = fmaf(a, bv.x, acc[i][0]);
        acc[i][1] = fmaf(a, bv.y, acc[i][1]);
        acc[i][2] = fmaf(a, bv.z, acc[i][2]);
        acc[i][3] = fmaf(a, bv.w, acc[i][3]);
      }
    }
  }
  int cbase = c0 + tx * 4;
#pragma unroll
  for (int i = 0; i < 8; ++i) {
    int r = rowbase + ty * 8 + i;
    if (r < nrows) {
      ushort4 o;
      o.x = f2bf(acc[i][0]); o.y = f2bf(acc[i][1]);
      o.z = f2bf(acc[i][2]); o.w = f2bf(acc[i][3]);
      *reinterpret_cast<ushort4*>(&C[(size_t)r * DD + cbase]) = o;
    }
  }
}

__global__ __launch_bounds__(256) void k_gemm1_hist(
    const float* __restrict__ A, const float* __restrict__ B, ushort* __restrict__ C,
    int nrows, const int* __restrict__ dst, int* __restrict__ deg, int ecnt,
    int gblocks, int hblocks) {
  __shared__ float Bs[DD * 64];
  int bx = blockIdx.x;
  if (bx < gblocks) {
    gemm_f32_body(A, B, C, nrows, bx, Bs);
  } else {
    int hb = bx - gblocks;
    int stride = hblocks * 256;
    for (int e = hb * 256 + threadIdx.x; e < ecnt; e += stride)
      atomicAdd(&deg[dst[e]], 1);
  }
}

// ---------------- GEMM2: bf16 A [nrows,128] @ f32 B -> bf16 C ----------------

__global__ __launch_bounds__(256) void k_gemmb(const ushort* __restrict__ A,
                                               const float* __restrict__ B,
                                               ushort* __restrict__ C, int nrows) {
  __shared__ float Bs[DD * 64];
  int tid = threadIdx.x;
  int tx = tid & 15, ty = tid >> 4;
  int rowbase = (blockIdx.x >> 1) * 128;
  int c0 = (blockIdx.x & 1) * 64;
  {
    int kk = tid >> 4;
    int cc = (tid & 15) * 4;
#pragma unroll
    for (int p = 0; p < 8; ++p) {
      int k = p * 16 + kk;
      float4 bv = *reinterpret_cast<const float4*>(&B[k * DD + c0 + cc]);
      *reinterpret_cast<float4*>(&Bs[k * 64 + cc]) = bv;
    }
  }
  __syncthreads();
  float acc[8][4];
#pragma unroll
  for (int i = 0; i < 8; ++i)
#pragma unroll
    for (int j = 0; j < 4; ++j) acc[i][j] = 0.f;
  int rl[8];
#pragma unroll
  for (int i = 0; i < 8; ++i) {
    int r = rowbase + ty * 8 + i;
    rl[i] = (r < nrows) ? r : (nrows - 1);
  }
  const uint4* A16 = reinterpret_cast<const uint4*>(A);  // 16B = 8 bf16
  for (int kq = 0; kq < 16; ++kq) {  // 8 dims per step
    uint4 av[8];
#pragma unroll
    for (int i = 0; i < 8; ++i) av[i] = A16[(size_t)rl[i] * 16 + kq];
#pragma unroll
    for (int kk = 0; kk < 8; ++kk) {
      float4 bv = *reinterpret_cast<const float4*>(&Bs[(kq * 8 + kk) * 64 + tx * 4]);
#pragma unroll
      for (int i = 0; i < 8; ++i) {
        uint w = (kk < 2) ? av[i].x : (kk < 4) ? av[i].y : (kk < 6) ? av[i].z : av[i].w;
        float a = (kk & 1) ? bfhi(w) : bflo(w);
        acc[i][0] = fmaf(a, bv.x, acc[i][0]);
        acc[i][1] = fmaf(a, bv.y, acc[i][1]);
        acc[i][2] = fmaf(a, bv.z, acc[i][2]);
        acc[i][3] = fmaf(a, bv.w, acc[i][3]);
      }
    }
  }
  int cbase = c0 + tx * 4;
#pragma unroll
  for (int i = 0; i < 8; ++i) {
    int r = rowbase + ty * 8 + i;
    if (r < nrows) {
      ushort4 o;
      o.x = f2bf(acc[i][0]); o.y = f2bf(acc[i][1]);
      o.z = f2bf(acc[i][2]); o.w = f2bf(acc[i][3]);
      *reinterpret_cast<ushort4*>(&C[(size_t)r * DD + cbase]) = o;
    }
  }
}

// ---------------- edge accumulate: 8-deep batches, scalar 4B CSR ----------------
// Wave = node i; lane owns dims {2*lane, 2*lane+1}. CSR base/count readfirstlane'd ->
// entries come in via s_load (SGPR), src/nw decode is SALU + 1 cvt.

static __device__ __forceinline__ void edge_accum(
    const uint* __restrict__ xw32, const uint* __restrict__ csr,
    int start, int cnt, uint lane, float& acc0, float& acc1) {
  const uint* cs = csr + __builtin_amdgcn_readfirstlane(start);
  int rem = __builtin_amdgcn_readfirstlane(cnt);
  uint c[8];
  if (rem >= 8) {
#pragma unroll
    for (int j = 0; j < 8; ++j) c[j] = cs[j];
    cs += 8;
  }
  while (rem >= 16) {
    uint v[8];
#pragma unroll
    for (int j = 0; j < 8; ++j) v[j] = xw32[((c[j] & 0xFFFFu) << 6) + lane];
    uint cn[8];
#pragma unroll
    for (int j = 0; j < 8; ++j) cn[j] = cs[j];
#pragma unroll
    for (int j = 0; j < 8; ++j) {
      float nw = __half2float(__ushort_as_half((ushort)(c[j] >> 16)));
      acc0 = fmaf(bflo(v[j]), nw, acc0);
      acc1 = fmaf(bfhi(v[j]), nw, acc1);
    }
#pragma unroll
    for (int j = 0; j < 8; ++j) c[j] = cn[j];
    cs += 8; rem -= 8;
  }
  if (rem >= 8) {
    uint v[8];
#pragma unroll
    for (int j = 0; j < 8; ++j) v[j] = xw32[((c[j] & 0xFFFFu) << 6) + lane];
#pragma unroll
    for (int j = 0; j < 8; ++j) {
      float nw = __half2float(__ushort_as_half((ushort)(c[j] >> 16)));
      acc0 = fmaf(bflo(v[j]), nw, acc0);
      acc1 = fmaf(bfhi(v[j]), nw, acc1);
    }
    rem -= 8;
  }
  if (rem > 0) {
    uint ct[8];
#pragma unroll
    for (int j = 0; j < 8; ++j) ct[j] = cs[j < rem ? j : 0];
    uint v[8];
#pragma unroll
    for (int j = 0; j < 8; ++j) v[j] = xw32[((ct[j] & 0xFFFFu) << 6) + lane];
#pragma unroll
    for (int j = 0; j < 8; ++j) {
      float nw = (j < rem) ? __half2float(__ushort_as_half((ushort)(ct[j] >> 16))) : 0.f;
      acc0 = fmaf(bflo(v[j]), nw, acc0);
      acc1 = fmaf(bfhi(v[j]), nw, acc1);
    }
  }
}

// ---------------- agg1: gather + self + bias + LN + ReLU -> bf16 h1 ----------------

__global__ __launch_bounds__(256) void k_agg1(
    const ushort* __restrict__ xw, const uint* __restrict__ csr,
    const int* __restrict__ rowoff, const int* __restrict__ deg,
    const float* __restrict__ dinv, const float* __restrict__ bias,
    const float* __restrict__ gam, const float* __restrict__ bet,
    uint* __restrict__ outp, int n) {
  int wv = threadIdx.x >> 6, lane = threadIdx.x & 63;
  int i = blockIdx.x * 4 + wv;
  if (i >= n) return;
  int start = rowoff[i], cnt = deg[i];
  float di = dinv[i];
  const uint* xw32 = (const uint*)xw;
  float2 bv = ((const float2*)bias)[lane];
  uint su = xw32[((uint)i << 6) + lane];
  float sw = 2.f * di * di;
  float acc0 = fmaf(bflo(su), sw, bv.x);
  float acc1 = fmaf(bfhi(su), sw, bv.y);
  edge_accum(xw32, csr, start, cnt, (uint)lane, acc0, acc1);
  // LayerNorm over 128 dims (wave-local)
  float s = acc0 + acc1;
#pragma unroll
  for (int off = 32; off > 0; off >>= 1) s += __shfl_xor(s, off);
  float mu = s * (1.f / DD);
  float c0 = acc0 - mu, c1 = acc1 - mu;
  float q = c0 * c0 + c1 * c1;
#pragma unroll
  for (int off = 32; off > 0; off >>= 1) q += __shfl_xor(q, off);
  float rstd = rsqrtf(q * (1.f / DD) + EPSV);
  float2 gv = ((const float2*)gam)[lane];
  float2 tv = ((const float2*)bet)[lane];
  float h0 = fmaxf(fmaf(c0 * rstd, gv.x, tv.x), 0.f);
  float h1 = fmaxf(fmaf(c1 * rstd, gv.y, tv.y), 0.f);
  uint packed = (uint)f2bf(h0) | ((uint)f2bf(h1) << 16);
  __builtin_nontemporal_store(packed, &outp[((uint)i << 6) + lane]);
}

// ---------------- agg2: gather + LN + SE + residual + ReLU -> fp32 out ----------------

__global__ __launch_bounds__(256) void k_agg2(
    const ushort* __restrict__ xw, const uint* __restrict__ csr,
    const int* __restrict__ rowoff, const int* __restrict__ deg,
    const float* __restrict__ dinv, const float* __restrict__ bias,
    const float* __restrict__ gam, const float* __restrict__ bet,
    const float* __restrict__ Ws, const float* __restrict__ bs,
    const float* __restrict__ We, const float* __restrict__ be,
    const float* __restrict__ xin, float* __restrict__ outp, int n) {
  int wv = threadIdx.x >> 6, lane = threadIdx.x & 63;
  int i = blockIdx.x * 4 + wv;
  if (i >= n) return;
  int start = rowoff[i], cnt = deg[i];
  float di = dinv[i];
  const uint* xw32 = (const uint*)xw;
  float2 bv = ((const float2*)bias)[lane];
  uint su = xw32[((uint)i << 6) + lane];
  float sw = 2.f * di * di;
  float acc0 = fmaf(bflo(su), sw, bv.x);
  float acc1 = fmaf(bfhi(su), sw, bv.y);
  edge_accum(xw32, csr, start, cnt, (uint)lane, acc0, acc1);
  // LayerNorm
  float s = acc0 + acc1;
#pragma unroll
  for (int off = 32; off > 0; off >>= 1) s += __shfl_xor(s, off);
  float mu = s * (1.f / DD);
  float c0 = acc0 - mu, c1 = acc1 - mu;
  float q = c0 * c0 + c1 * c1;
#pragma unroll
  for (int off = 32; off > 0; off >>= 1) q += __shfl_xor(q, off);
  float rstd = rsqrtf(q * (1.f / DD) + EPSV);
  float2 gv = ((const float2*)gam)[lane];
  float2 tv = ((const float2*)bet)[lane];
  float h0 = fmaf(c0 * rstd, gv.x, tv.x);
  float h1 = fmaf(c1 * rstd, gv.y, tv.y);
  // SE: s16 = relu(h @ Ws + bs); w = sigmoid(s16 @ We + be)
  float pj[HH];
  const float* wr0 = &Ws[(2 * lane) * HH];
  const float* wr1 = &Ws[(2 * lane + 1) * HH];
#pragma unroll
  for (int j = 0; j < HH; ++j) pj[j] = h0 * wr0[j] + h1 * wr1[j];
#pragma unroll
  for (int off = 32; off > 0; off >>= 1) {
#pragma unroll
    for (int j = 0; j < HH; ++j) pj[j] += __shfl_xor(pj[j], off);
  }
  float2 bev = ((const float2*)be)[lane];
  float wacc0 = bev.x, wacc1 = bev.y;
#pragma unroll
  for (int j = 0; j < HH; ++j) {
    float sj = fmaxf(pj[j] + bs[j], 0.f);
    float2 wev = ((const float2*)(We + j * DD))[lane];
    wacc0 = fmaf(sj, wev.x, wacc0);
    wacc1 = fmaf(sj, wev.y, wacc1);
  }
  float w0 = 1.f / (1.f + __expf(-wacc0));
  float w1 = 1.f / (1.f + __expf(-wacc1));
  float2 xr = ((const float2*)(xin + (size_t)i * DD))[lane];
  float2 o;
  o.x = fmaxf(fmaf(h0, w0, xr.x), 0.f);
  o.y = fmaxf(fmaf(h1, w1, xr.y), 0.f);
  ((float2*)(outp + (size_t)i * DD))[lane] = o;
}

// ---------------- launcher ----------------

extern "C" void kernel_launch(void* const* d_in, const int* in_sizes, int n_in,
                              void* d_out, int out_size, void* d_ws, size_t ws_size,
                              hipStream_t stream) {
  const float* x   = (const float*)d_in[0];
  const int*   ei  = (const int*)d_in[1];
  const float* W1  = (const float*)d_in[2];
  const float* b1  = (const float*)d_in[3];
  const float* g1  = (const float*)d_in[4];
  const float* be1 = (const float*)d_in[5];
  const float* W2  = (const float*)d_in[6];
  const float* b2  = (const float*)d_in[7];
  const float* g2  = (const float*)d_in[8];
  const float* be2 = (const float*)d_in[9];
  const float* Ws  = (const float*)d_in[10];
  const float* bs  = (const float*)d_in[11];
  const float* We  = (const float*)d_in[12];
  const float* bee = (const float*)d_in[13];
  float* outp = (float*)d_out;

  int n    = in_sizes[0] / DD;
  int ecnt = in_sizes[1] / 2;
  const int* src = ei;
  const int* dst = ei + ecnt;

  char* w = (char*)d_ws;
  ushort* xw    = (ushort*)w; w += (size_t)n * DD * 2;
  uint*   h1    = (uint*)w;   w += (size_t)n * DD * 2;   // bf16 packed
  int*    deg   = (int*)w;    w += (size_t)n * 4;
  int*    cursor= (int*)w;    w += (size_t)n * 4;
  int*    rowoff= (int*)w;    w += (size_t)n * 4;
  float*  dinv  = (float*)w;  w += (size_t)n * 4;
  int*    bsum  = (int*)w;    w += 64 * 4;
  uint*   csr   = (uint*)w;   w += ((size_t)ecnt + 16) * 4;  // 4B packed entries

  hipMemsetAsync(deg, 0, (size_t)n * 4, stream);

  const int TB = 256;
  int gblocks = ((n + 127) / 128) * 2;
  int hblocks = 2048;
  k_gemm1_hist<<<gblocks + hblocks, TB, 0, stream>>>(x, W1, xw, n, dst, deg, ecnt,
                                                     gblocks, hblocks);
  int nb = (n + SCAN_T * SCAN_I - 1) / (SCAN_T * SCAN_I);
  k_scan1<<<nb, SCAN_T, 0, stream>>>(deg, bsum, n);
  k_scan2<<<nb, SCAN_T, 0, stream>>>(deg, bsum, rowoff, cursor, dinv, n);
  int eb = (ecnt + TB - 1) / TB;
  k_fill<<<eb, TB, 0, stream>>>(src, dst, dinv, cursor, csr, ecnt);

  int nb4 = (n + 3) / 4;
  k_agg1<<<nb4, TB, 0, stream>>>(xw, csr, rowoff, deg, dinv, b1, g1, be1, h1, n);
  k_gemmb<<<gblocks, TB, 0, stream>>>((const ushort*)h1, W2, xw, n);
  k_agg2<<<nb4, TB, 0, stream>>>(xw, csr, rowoff, deg, dinv, b2, g2, be2,
                                 Ws, bs, We, bee, x, outp, n);
}